// Round 17
// baseline (303.819 us; speedup 1.0000x reference)
//
#include <hip/hip_runtime.h>
#include <hip/hip_bf16.h>

typedef __bf16 bf16_t;
typedef __bf16 bf16x8 __attribute__((ext_vector_type(8)));
typedef float f32x4 __attribute__((ext_vector_type(4)));

#define MFMA16x16(a, b, c) __builtin_amdgcn_mfma_f32_16x16x32_bf16((a), (b), (c), 0, 0, 0)

constexpr int DIM = 192;
constexpr int NHEAD = 6;
constexpr int NWIN = 2048;   // 32 * 8 * 8 windows
constexpr int WTOK = 64;     // tokens per 8x8 window

// ================= merged frag-linear weight converter =================
// Fragment for mfma_16x16x32: lane&15 = row, k = (lane>>4)*8+e.
// Stored as [frag][lane][8] so a wave's load = base + lane*16B (1 coalesced KB).
// Ranges: [0,216*64) qkv | [.,288*64) proj | [.,576*64) w1 | [.,864*64) w2.
__global__ __launch_bounds__(256) void cvt_all(const float* __restrict__ qkv,
                                               const float* __restrict__ proj,
                                               const float* __restrict__ w1,
                                               const float* __restrict__ w2,
                                               bf16_t* __restrict__ qkvwf,
                                               bf16_t* __restrict__ pwf,
                                               bf16_t* __restrict__ w1f,
                                               bf16_t* __restrict__ w2f) {
    const int t = blockIdx.x * 256 + threadIdx.x;
    const int lane = t & 63;
    const int r15 = lane & 15, c8 = (lane >> 4) * 8;
    const float* sp;
    bf16_t* dp;
    if (t < 216 * 64) {
        const int f = t >> 6;
        const int nt = f & 1, kk = (f >> 1) % 6, ph = f / 12;
        sp = qkv + (ph * 32 + nt * 16 + r15) * 192 + kk * 32 + c8;
        dp = qkvwf + (size_t)t * 8;
    } else if (t < 288 * 64) {
        const int f = (t >> 6) - 216;
        const int nt = f % 3, kk = (f / 3) % 6, wv = f / 18;
        sp = proj + (wv * 48 + nt * 16 + r15) * 192 + kk * 32 + c8;
        dp = pwf + (size_t)(t - 216 * 64) * 8;
    } else if (t < 576 * 64) {
        const int f = (t >> 6) - 288;
        const int nt = f % 3, kk = (f / 3) % 6, q = f / 18;
        const int wv = q & 3, kc = q >> 2;
        sp = w1 + (kc * 192 + wv * 48 + nt * 16 + r15) * 192 + kk * 32 + c8;
        dp = w1f + (size_t)(t - 288 * 64) * 8;
    } else {
        const int f = (t >> 6) - 576;
        const int nt = f % 3, kk = (f / 3) % 6, q = f / 18;
        const int wv = q & 3, kc = q >> 2;
        sp = w2 + (size_t)(wv * 48 + nt * 16 + r15) * 768 + kc * 192 + kk * 32 + c8;
        dp = w2f + (size_t)(t - 576 * 64) * 8;
    }
#pragma unroll
    for (int e = 0; e < 8; ++e) dp[e] = (bf16_t)sp[e];
}

// ---------------- LN1 + roll + window partition -> frag-linear y ----------------
__global__ __launch_bounds__(256) void ln_win_kernel(const float* __restrict__ in,
                                                     const float* __restrict__ g,
                                                     const float* __restrict__ bta,
                                                     bf16_t* __restrict__ ywf) {
    __shared__ bf16_t y_s[64][200];
    const int tid = threadIdx.x, lane = tid & 63, wv = tid >> 6;
    const int win = blockIdx.x;
    const int b_ = win >> 6, hb = (win >> 3) & 7, wb = win & 7;
    const float gv0 = g[lane], gv1 = g[lane + 64], gv2 = g[lane + 128];
    const float bv0 = bta[lane], bv1 = bta[lane + 64], bv2 = bta[lane + 128];
    for (int i = 0; i < 16; ++i) {
        const int n = wv * 16 + i;
        const int th = n >> 3, tw = n & 7;
        const int hh = (hb * 8 + th + 4) & 63;
        const int ww = (wb * 8 + tw + 4) & 63;
        const size_t src = ((size_t)(b_ * 64 + hh) * 64 + ww) * DIM;
        const float v0 = in[src + lane], v1 = in[src + lane + 64], v2 = in[src + lane + 128];
        float sm = v0 + v1 + v2;
        float q = v0 * v0 + v1 * v1 + v2 * v2;
#pragma unroll
        for (int m = 1; m < 64; m <<= 1) {
            sm += __shfl_xor(sm, m);
            q += __shfl_xor(q, m);
        }
        const float mu = sm * (1.0f / DIM);
        const float inv = rsqrtf(q * (1.0f / DIM) - mu * mu + 1e-5f);
        y_s[n][lane]       = (bf16_t)((v0 - mu) * inv * gv0 + bv0);
        y_s[n][lane + 64]  = (bf16_t)((v1 - mu) * inv * gv1 + bv1);
        y_s[n][lane + 128] = (bf16_t)((v2 - mu) * inv * gv2 + bv2);
    }
    __syncthreads();
    bf16_t* dst = ywf + (size_t)win * 12288;
    for (int j = tid; j < 1536; j += 256) {
        const int f = j >> 6, ln = j & 63;
        const int mt = f & 3, kk = f >> 2;
        const int row = mt * 16 + (ln & 15), col = kk * 32 + (ln >> 4) * 8;
        *reinterpret_cast<bf16x8*>(dst + (size_t)j * 8) =
            *reinterpret_cast<const bf16x8*>(&y_s[row][col]);
    }
}

// ---------------- attention: one WAVE per (window, head), fused QKV kk-loop ----------------
__global__ __launch_bounds__(64, 3) void attn_kernel(const bf16_t* __restrict__ ywf,
                                                     const bf16_t* __restrict__ qkvwf,
                                                     const float* __restrict__ qkvb,
                                                     const float* __restrict__ relb,
                                                     bf16_t* __restrict__ aout) {
    __shared__ bf16_t scr[6400];
    const int lane = threadIdx.x;
    const int l15 = lane & 15, l4 = lane >> 4;
    // XCD-aware bijective swizzle: all 6 heads of a window land on the SAME XCD.
    const int wh = (blockIdx.x & 7) * ((NWIN * NHEAD) >> 3) + (blockIdx.x >> 3);
    const int win = wh / 6;
    const int h = wh - win * 6;
    const bf16_t* ywin = ywf + (size_t)win * 12288;

    bf16_t* tb = scr;           // q/k transpose buf (stride 40), later P (stride 64, swizzled)
    bf16_t* vtb = scr + 4096;   // [32 d][64 tok] stride 72

    // ---- fused QKV GEMM: A-frags loaded ONCE per kk; 3 accumulator sets ----
    f32x4 aQ[4][2] = {}, aK[4][2] = {}, aV[4][2] = {};
#pragma unroll
    for (int kk = 0; kk < 6; ++kk) {
        bf16x8 a[4];
#pragma unroll
        for (int mt = 0; mt < 4; ++mt)
            a[mt] = *reinterpret_cast<const bf16x8*>(ywin + ((kk * 4 + mt) << 9) + lane * 8);
        bf16x8 bq[2], bk2[2], bv[2];
#pragma unroll
        for (int nt = 0; nt < 2; ++nt) {
            bq[nt] = *reinterpret_cast<const bf16x8*>(
                qkvwf + (size_t)(((((h) * 6 + kk) << 1) + nt) << 9) + lane * 8);
            bk2[nt] = *reinterpret_cast<const bf16x8*>(
                qkvwf + (size_t)(((((6 + h) * 6 + kk) << 1) + nt) << 9) + lane * 8);
            bv[nt] = *reinterpret_cast<const bf16x8*>(
                qkvwf + (size_t)(((((12 + h) * 6 + kk) << 1) + nt) << 9) + lane * 8);
        }
        __builtin_amdgcn_s_setprio(1);
#pragma unroll
        for (int mt = 0; mt < 4; ++mt)
#pragma unroll
            for (int nt = 0; nt < 2; ++nt) {
                aQ[mt][nt] = MFMA16x16(a[mt], bq[nt], aQ[mt][nt]);
                aK[mt][nt] = MFMA16x16(a[mt], bk2[nt], aK[mt][nt]);
                aV[mt][nt] = MFMA16x16(a[mt], bv[nt], aV[mt][nt]);
            }
        __builtin_amdgcn_s_setprio(0);
    }

    // ---- V epilogue -> vtb[d][tok] ----
#pragma unroll
    for (int nt = 0; nt < 2; ++nt) {
        const int d = nt * 16 + l15;
        const float bias = qkvb[(12 + h) * 32 + d];
#pragma unroll
        for (int mt = 0; mt < 4; ++mt)
#pragma unroll
            for (int r = 0; r < 4; ++r)
                vtb[d * 72 + mt * 16 + l4 * 4 + r] = (bf16_t)(aV[mt][nt][r] + bias);
    }
    // ---- Q epilogue -> tb[tok][d] stride 40, then load aq frags ----
#pragma unroll
    for (int nt = 0; nt < 2; ++nt) {
        const int d = nt * 16 + l15;
        const float bias = qkvb[h * 32 + d];
#pragma unroll
        for (int mt = 0; mt < 4; ++mt)
#pragma unroll
            for (int r = 0; r < 4; ++r)
                tb[(mt * 16 + l4 * 4 + r) * 40 + d] =
                    (bf16_t)((aQ[mt][nt][r] + bias) * 0.17677669529663689f);
    }
    bf16x8 aq[4];
#pragma unroll
    for (int mt = 0; mt < 4; ++mt)
        aq[mt] = *reinterpret_cast<const bf16x8*>(&tb[(mt * 16 + l15) * 40 + l4 * 8]);

    // ---- K epilogue -> tb (single-wave in-order DS, overwrite OK) ----
#pragma unroll
    for (int nt = 0; nt < 2; ++nt) {
        const int d = nt * 16 + l15;
        const float bias = qkvb[(6 + h) * 32 + d];
#pragma unroll
        for (int mt = 0; mt < 4; ++mt)
#pragma unroll
            for (int r = 0; r < 4; ++r)
                tb[(mt * 16 + l4 * 4 + r) * 40 + d] = (bf16_t)(aK[mt][nt][r] + bias);
    }
    bf16x8 bk[4];
#pragma unroll
    for (int nt = 0; nt < 4; ++nt)
        bk[nt] = *reinterpret_cast<const bf16x8*>(&tb[(nt * 16 + l15) * 40 + l4 * 8]);

    // ---- S = q @ k^T : 64x64, K=32 ----
    f32x4 s[4][4] = {};
    __builtin_amdgcn_s_setprio(1);
#pragma unroll
    for (int mt = 0; mt < 4; ++mt)
#pragma unroll
        for (int nt = 0; nt < 4; ++nt)
            s[mt][nt] = MFMA16x16(aq[mt], bk[nt], s[mt][nt]);
    __builtin_amdgcn_s_setprio(0);

    // ---- rel bias + shift mask + softmax; P XOR-swizzled into tb ----
    const int hb = (win >> 3) & 7, wb = win & 7;
    int colc[4], colreg[4];
#pragma unroll
    for (int nt = 0; nt < 4; ++nt) {
        const int m = nt * 16 + l15;
        const int mh = m >> 3, mw = m & 7;
        colc[nt] = mh * 15 + mw;
        const int gh = hb * 8 + mh, gw = wb * 8 + mw;
        const int rh = (gh < 56) ? 0 : ((gh < 60) ? 1 : 2);
        const int rw = (gw < 56) ? 0 : ((gw < 60) ? 1 : 2);
        colreg[nt] = rh * 3 + rw;
    }
#pragma unroll
    for (int mt = 0; mt < 4; ++mt) {
#pragma unroll
        for (int r = 0; r < 4; ++r) {
            const int n = mt * 16 + l4 * 4 + r;
            const int nh = n >> 3, nw = n & 7;
            const int rowc = nh * 15 + nw + 112;
            const int gh = hb * 8 + nh, gw = wb * 8 + nw;
            const int rh = (gh < 56) ? 0 : ((gh < 60) ? 1 : 2);
            const int rw = (gw < 56) ? 0 : ((gw < 60) ? 1 : 2);
            const int rreg = rh * 3 + rw;
            float vals[4];
            float mx = -1e30f;
#pragma unroll
            for (int nt = 0; nt < 4; ++nt) {
                float v = s[mt][nt][r] + relb[(rowc - colc[nt]) * NHEAD + h];
                if (rreg != colreg[nt]) v -= 100.0f;
                vals[nt] = v;
                mx = fmaxf(mx, v);
            }
            mx = fmaxf(mx, __shfl_xor(mx, 1));
            mx = fmaxf(mx, __shfl_xor(mx, 2));
            mx = fmaxf(mx, __shfl_xor(mx, 4));
            mx = fmaxf(mx, __shfl_xor(mx, 8));
            float sum = 0.f;
#pragma unroll
            for (int nt = 0; nt < 4; ++nt) {
                vals[nt] = __expf(vals[nt] - mx);
                sum += vals[nt];
            }
            sum += __shfl_xor(sum, 1);
            sum += __shfl_xor(sum, 2);
            sum += __shfl_xor(sum, 4);
            sum += __shfl_xor(sum, 8);
            const float inv = 1.0f / sum;
            const int nsw = n & 7;
#pragma unroll
            for (int nt = 0; nt < 4; ++nt) {
                const int tk = nt * 16 + l15;
                tb[n * 64 + (((tk >> 3) ^ nsw) << 3) + (tk & 7)] = (bf16_t)(vals[nt] * inv);
            }
        }
    }

    // ---- O = P @ V : 64x32, K=64 ----
    f32x4 o[4][2] = {};
#pragma unroll
    for (int kk = 0; kk < 2; ++kk) {
        bf16x8 a[4], b[2];
#pragma unroll
        for (int mt = 0; mt < 4; ++mt) {
            const int tq = mt * 16 + l15;
            a[mt] = *reinterpret_cast<const bf16x8*>(&tb[tq * 64 + (((kk * 4 + l4) ^ (tq & 7)) << 3)]);
        }
#pragma unroll
        for (int nt = 0; nt < 2; ++nt)
            b[nt] = *reinterpret_cast<const bf16x8*>(&vtb[(nt * 16 + l15) * 72 + kk * 32 + l4 * 8]);
        __builtin_amdgcn_s_setprio(1);
#pragma unroll
        for (int mt = 0; mt < 4; ++mt)
#pragma unroll
            for (int nt = 0; nt < 2; ++nt)
                o[mt][nt] = MFMA16x16(a[mt], b[nt], o[mt][nt]);
        __builtin_amdgcn_s_setprio(0);
    }
    bf16_t* op = aout + (size_t)win * (WTOK * DIM) + h * 32;
#pragma unroll
    for (int mt = 0; mt < 4; ++mt)
#pragma unroll
        for (int nt = 0; nt < 2; ++nt)
#pragma unroll
            for (int r = 0; r < 4; ++r) {
                const int n = mt * 16 + l4 * 4 + r;
                op[n * DIM + nt * 16 + l15] = (bf16_t)o[mt][nt][r];
            }
}

// ---------------- proj + window-reverse + roll-back + residual -> x2 (d_out) ----------------
__global__ __launch_bounds__(256) void proj_kernel(const bf16_t* __restrict__ ain,
                                                   const bf16_t* __restrict__ pwf,
                                                   const float* __restrict__ pbias,
                                                   const float* __restrict__ x,
                                                   float* __restrict__ x2) {
    __shared__ bf16_t a_s[64][200];
    const int tid = threadIdx.x;
    const int lane = tid & 63;
    const int wv = tid >> 6;
    const int win = blockIdx.x;
    const int l15 = lane & 15, l4 = lane >> 4;

    const bf16_t* asrc = ain + (size_t)win * (WTOK * DIM);
    for (int i = tid; i < WTOK * DIM / 8; i += 256) {
        const int idx = i * 8;
        *reinterpret_cast<bf16x8*>(&a_s[idx / DIM][idx % DIM]) =
            *reinterpret_cast<const bf16x8*>(asrc + idx);
    }
    __syncthreads();

    const int n0 = wv * 48;
    f32x4 acc[4][3] = {};
    for (int kk = 0; kk < 6; ++kk) {
        const int c0 = kk * 32 + l4 * 8;
        bf16x8 a[4], b[3];
#pragma unroll
        for (int mt = 0; mt < 4; ++mt)
            a[mt] = *reinterpret_cast<const bf16x8*>(&a_s[mt * 16 + l15][c0]);
#pragma unroll
        for (int nt = 0; nt < 3; ++nt)
            b[nt] = *reinterpret_cast<const bf16x8*>(
                pwf + (size_t)(((wv * 6 + kk) * 3 + nt) << 9) + lane * 8);
        __builtin_amdgcn_s_setprio(1);
#pragma unroll
        for (int mt = 0; mt < 4; ++mt)
#pragma unroll
            for (int nt = 0; nt < 3; ++nt)
                acc[mt][nt] = MFMA16x16(a[mt], b[nt], acc[mt][nt]);
        __builtin_amdgcn_s_setprio(0);
    }
    const int b_ = win >> 6, hb = (win >> 3) & 7, wb = win & 7;
#pragma unroll
    for (int mt = 0; mt < 4; ++mt)
#pragma unroll
        for (int r = 0; r < 4; ++r) {
            const int n = mt * 16 + l4 * 4 + r;
            const int th = n >> 3, tw = n & 7;
            const int hh = (hb * 8 + th + 4) & 63;
            const int ww = (wb * 8 + tw + 4) & 63;
            const size_t row = ((size_t)(b_ * 64 + hh) * 64 + ww) * DIM;
#pragma unroll
            for (int nt = 0; nt < 3; ++nt) {
                const int col = n0 + nt * 16 + l15;
                x2[row + col] = acc[mt][nt][r] + pbias[col] + x[row + col];
            }
        }
}

// fast GELU, tanh form
__device__ __forceinline__ float gelu_f(float v) {
    const float x2 = v * v;
    const float inner = fmaf(0.044715f * x2, v, v);
    const float e = __expf(inner * 1.5957691216057308f);
    const float r = __builtin_amdgcn_rcpf(e + 1.0f);
    return v - v * r;
}

// ---------------- fused LN2 + MLP (round-14 proven body, (256,3), + setprio) ----------------
__global__ __launch_bounds__(256, 3) void mlp_kernel(const float* __restrict__ g,
                                                     const float* __restrict__ bta,
                                                     const bf16_t* __restrict__ w1f,
                                                     const float* __restrict__ b1,
                                                     const bf16_t* __restrict__ w2f,
                                                     const float* __restrict__ b2,
                                                     float* __restrict__ xout) {
    __shared__ bf16_t z_s[64][200];
    __shared__ bf16_t h_s[64][200];
    const int tid = threadIdx.x, lane = tid & 63, wv = tid >> 6;
    const int l15 = lane & 15, l4 = lane >> 4;
    const size_t t0 = (size_t)blockIdx.x * 64;
    const int n0 = wv * 48;

    // ---- LN2 on this block's 64 rows of x2 -> z_s ----
    {
        const float gv0 = g[lane], gv1 = g[lane + 64], gv2 = g[lane + 128];
        const float bv0 = bta[lane], bv1 = bta[lane + 64], bv2 = bta[lane + 128];
        for (int i = 0; i < 16; ++i) {
            const int n = wv * 16 + i;
            const size_t src = (t0 + n) * DIM;
            const float v0 = xout[src + lane], v1 = xout[src + lane + 64], v2 = xout[src + lane + 128];
            float sm = v0 + v1 + v2;
            float q = v0 * v0 + v1 * v1 + v2 * v2;
#pragma unroll
            for (int m = 1; m < 64; m <<= 1) {
                sm += __shfl_xor(sm, m);
                q += __shfl_xor(q, m);
            }
            const float mu = sm * (1.0f / DIM);
            const float inv = rsqrtf(q * (1.0f / DIM) - mu * mu + 1e-5f);
            z_s[n][lane]       = (bf16_t)((v0 - mu) * inv * gv0 + bv0);
            z_s[n][lane + 64]  = (bf16_t)((v1 - mu) * inv * gv1 + bv1);
            z_s[n][lane + 128] = (bf16_t)((v2 - mu) * inv * gv2 + bv2);
        }
    }
    __syncthreads();

    f32x4 acc_o[4][3] = {};
    for (int kc = 0; kc < 4; ++kc) {
        const int fb = (kc * 4 + wv) * 18;
        f32x4 hacc[4][3] = {};
#pragma unroll
        for (int kk = 0; kk < 6; ++kk) {
            const int c0 = kk * 32 + l4 * 8;
            bf16x8 a[4], b[3];
#pragma unroll
            for (int mt = 0; mt < 4; ++mt)
                a[mt] = *reinterpret_cast<const bf16x8*>(&z_s[mt * 16 + l15][c0]);
#pragma unroll
            for (int nt = 0; nt < 3; ++nt)
                b[nt] = *reinterpret_cast<const bf16x8*>(
                    w1f + (size_t)((fb + kk * 3 + nt) << 9) + lane * 8);
            __builtin_amdgcn_s_setprio(1);
#pragma unroll
            for (int mt = 0; mt < 4; ++mt)
#pragma unroll
                for (int nt = 0; nt < 3; ++nt)
                    hacc[mt][nt] = MFMA16x16(a[mt], b[nt], hacc[mt][nt]);
            __builtin_amdgcn_s_setprio(0);
        }
        __syncthreads();  // previous GEMM2 done reading h_s
#pragma unroll
        for (int mt = 0; mt < 4; ++mt)
#pragma unroll
            for (int r = 0; r < 4; ++r) {
                const int n = mt * 16 + l4 * 4 + r;
#pragma unroll
                for (int nt = 0; nt < 3; ++nt) {
                    const int col = n0 + nt * 16 + l15;
                    h_s[n][col] = (bf16_t)gelu_f(hacc[mt][nt][r] + b1[kc * 192 + col]);
                }
            }
        __syncthreads();
        // GEMM2: acc_o += h_chunk @ w2_chunk^T
#pragma unroll
        for (int kk = 0; kk < 6; ++kk) {
            const int c0 = kk * 32 + l4 * 8;
            bf16x8 a[4], b[3];
#pragma unroll
            for (int mt = 0; mt < 4; ++mt)
                a[mt] = *reinterpret_cast<const bf16x8*>(&h_s[mt * 16 + l15][c0]);
#pragma unroll
            for (int nt = 0; nt < 3; ++nt)
                b[nt] = *reinterpret_cast<const bf16x8*>(
                    w2f + (size_t)((fb + kk * 3 + nt) << 9) + lane * 8);
            __builtin_amdgcn_s_setprio(1);
#pragma unroll
            for (int mt = 0; mt < 4; ++mt)
#pragma unroll
                for (int nt = 0; nt < 3; ++nt)
                    acc_o[mt][nt] = MFMA16x16(a[mt], b[nt], acc_o[mt][nt]);
            __builtin_amdgcn_s_setprio(0);
        }
    }
#pragma unroll
    for (int mt = 0; mt < 4; ++mt)
#pragma unroll
        for (int r = 0; r < 4; ++r) {
            const int n = mt * 16 + l4 * 4 + r;
            const size_t addr = (t0 + n) * DIM;
#pragma unroll
            for (int nt = 0; nt < 3; ++nt) {
                const int col = n0 + nt * 16 + l15;
                xout[addr + col] = acc_o[mt][nt][r] + b2[col] + xout[addr + col];
            }
        }
}

extern "C" void kernel_launch(void* const* d_in, const int* in_sizes, int n_in,
                              void* d_out, int out_size, void* d_ws, size_t ws_size,
                              hipStream_t stream) {
    const float* x      = (const float*)d_in[0];
    const float* ln1_g  = (const float*)d_in[1];
    const float* ln1_b  = (const float*)d_in[2];
    const float* qkv_w  = (const float*)d_in[3];
    const float* qkv_b  = (const float*)d_in[4];
    const float* proj_w = (const float*)d_in[5];
    const float* proj_b = (const float*)d_in[6];
    const float* relb   = (const float*)d_in[7];
    const float* ln2_g  = (const float*)d_in[8];
    const float* ln2_b  = (const float*)d_in[9];
    const float* mlp_w1 = (const float*)d_in[10];
    const float* mlp_b1 = (const float*)d_in[11];
    const float* mlp_w2 = (const float*)d_in[12];
    const float* mlp_b2 = (const float*)d_in[13];
    float* out = (float*)d_out;

    char* ws = (char*)d_ws;
    bf16_t* qkvwf = (bf16_t*)(ws + 0);                       // 221184 B
    bf16_t* pwf   = (bf16_t*)(ws + 221184);                  // 73728 B
    bf16_t* w1f   = (bf16_t*)(ws + 294912);                  // 294912 B
    bf16_t* w2f   = (bf16_t*)(ws + 589824);                  // 294912 B
    bf16_t* bufA  = (bf16_t*)(ws + 884736);                  // ywf (frag-linear)
    bf16_t* bufB  = (bf16_t*)(ws + 884736 + 50331648);       // attn_out

    cvt_all<<<216, 256, 0, stream>>>(qkv_w, proj_w, mlp_w1, mlp_w2, qkvwf, pwf, w1f, w2f);

    ln_win_kernel<<<NWIN, 256, 0, stream>>>(x, ln1_g, ln1_b, bufA);
    attn_kernel<<<NWIN * NHEAD, 64, 0, stream>>>(bufA, qkvwf, qkv_b, relb, bufB);
    proj_kernel<<<NWIN, 256, 0, stream>>>(bufB, pwf, proj_b, x, out);
    mlp_kernel<<<2048, 256, 0, stream>>>(ln2_g, ln2_b, w1f, mlp_b1, w2f, mlp_b2, out);
}

// Round 18
// 300.113 us; speedup vs baseline: 1.0124x; 1.0124x over previous
//
#include <hip/hip_runtime.h>
#include <hip/hip_bf16.h>

typedef __bf16 bf16_t;
typedef __bf16 bf16x8 __attribute__((ext_vector_type(8)));
typedef float f32x4 __attribute__((ext_vector_type(4)));

#define MFMA16x16(a, b, c) __builtin_amdgcn_mfma_f32_16x16x32_bf16((a), (b), (c), 0, 0, 0)

constexpr int DIM = 192;
constexpr int NHEAD = 6;
constexpr int NWIN = 2048;   // 32 * 8 * 8 windows
constexpr int WTOK = 64;     // tokens per 8x8 window

// ================= merged frag-linear weight converter =================
// Fragment for mfma_16x16x32: lane&15 = row, k = (lane>>4)*8+e.
// Stored as [frag][lane][8] so a wave's load = base + lane*16B (1 coalesced KB).
// Ranges: [0,216*64) qkv | [.,288*64) proj | [.,576*64) w1 | [.,864*64) w2.
__global__ __launch_bounds__(256) void cvt_all(const float* __restrict__ qkv,
                                               const float* __restrict__ proj,
                                               const float* __restrict__ w1,
                                               const float* __restrict__ w2,
                                               bf16_t* __restrict__ qkvwf,
                                               bf16_t* __restrict__ pwf,
                                               bf16_t* __restrict__ w1f,
                                               bf16_t* __restrict__ w2f) {
    const int t = blockIdx.x * 256 + threadIdx.x;
    const int lane = t & 63;
    const int r15 = lane & 15, c8 = (lane >> 4) * 8;
    const float* sp;
    bf16_t* dp;
    if (t < 216 * 64) {
        const int f = t >> 6;
        const int nt = f & 1, kk = (f >> 1) % 6, ph = f / 12;
        sp = qkv + (ph * 32 + nt * 16 + r15) * 192 + kk * 32 + c8;
        dp = qkvwf + (size_t)t * 8;
    } else if (t < 288 * 64) {
        const int f = (t >> 6) - 216;
        const int nt = f % 3, kk = (f / 3) % 6, wv = f / 18;
        sp = proj + (wv * 48 + nt * 16 + r15) * 192 + kk * 32 + c8;
        dp = pwf + (size_t)(t - 216 * 64) * 8;
    } else if (t < 576 * 64) {
        const int f = (t >> 6) - 288;
        const int nt = f % 3, kk = (f / 3) % 6, q = f / 18;
        const int wv = q & 3, kc = q >> 2;
        sp = w1 + (kc * 192 + wv * 48 + nt * 16 + r15) * 192 + kk * 32 + c8;
        dp = w1f + (size_t)(t - 288 * 64) * 8;
    } else {
        const int f = (t >> 6) - 576;
        const int nt = f % 3, kk = (f / 3) % 6, q = f / 18;
        const int wv = q & 3, kc = q >> 2;
        sp = w2 + (size_t)(wv * 48 + nt * 16 + r15) * 768 + kc * 192 + kk * 32 + c8;
        dp = w2f + (size_t)(t - 576 * 64) * 8;
    }
#pragma unroll
    for (int e = 0; e < 8; ++e) dp[e] = (bf16_t)sp[e];
}

// ---------------- LN1 + roll + window partition -> frag-linear y ----------------
__global__ __launch_bounds__(256) void ln_win_kernel(const float* __restrict__ in,
                                                     const float* __restrict__ g,
                                                     const float* __restrict__ bta,
                                                     bf16_t* __restrict__ ywf) {
    __shared__ bf16_t y_s[64][200];
    const int tid = threadIdx.x, lane = tid & 63, wv = tid >> 6;
    const int win = blockIdx.x;
    const int b_ = win >> 6, hb = (win >> 3) & 7, wb = win & 7;
    const float gv0 = g[lane], gv1 = g[lane + 64], gv2 = g[lane + 128];
    const float bv0 = bta[lane], bv1 = bta[lane + 64], bv2 = bta[lane + 128];
    for (int i = 0; i < 16; ++i) {
        const int n = wv * 16 + i;
        const int th = n >> 3, tw = n & 7;
        const int hh = (hb * 8 + th + 4) & 63;
        const int ww = (wb * 8 + tw + 4) & 63;
        const size_t src = ((size_t)(b_ * 64 + hh) * 64 + ww) * DIM;
        const float v0 = in[src + lane], v1 = in[src + lane + 64], v2 = in[src + lane + 128];
        float sm = v0 + v1 + v2;
        float q = v0 * v0 + v1 * v1 + v2 * v2;
#pragma unroll
        for (int m = 1; m < 64; m <<= 1) {
            sm += __shfl_xor(sm, m);
            q += __shfl_xor(q, m);
        }
        const float mu = sm * (1.0f / DIM);
        const float inv = rsqrtf(q * (1.0f / DIM) - mu * mu + 1e-5f);
        y_s[n][lane]       = (bf16_t)((v0 - mu) * inv * gv0 + bv0);
        y_s[n][lane + 64]  = (bf16_t)((v1 - mu) * inv * gv1 + bv1);
        y_s[n][lane + 128] = (bf16_t)((v2 - mu) * inv * gv2 + bv2);
    }
    __syncthreads();
    bf16_t* dst = ywf + (size_t)win * 12288;
    for (int j = tid; j < 1536; j += 256) {
        const int f = j >> 6, ln = j & 63;
        const int mt = f & 3, kk = f >> 2;
        const int row = mt * 16 + (ln & 15), col = kk * 32 + (ln >> 4) * 8;
        *reinterpret_cast<bf16x8*>(dst + (size_t)j * 8) =
            *reinterpret_cast<const bf16x8*>(&y_s[row][col]);
    }
}

// ---------------- attention: one WAVE per (window, head), fused QKV kk-loop ----------------
// Output written FRAG-LINEAR: awf[win][h*4+mt][lane][8] (head h = proj k-chunk h).
__global__ __launch_bounds__(64, 3) void attn_kernel(const bf16_t* __restrict__ ywf,
                                                     const bf16_t* __restrict__ qkvwf,
                                                     const float* __restrict__ qkvb,
                                                     const float* __restrict__ relb,
                                                     bf16_t* __restrict__ awf) {
    __shared__ bf16_t scr[6400];
    const int lane = threadIdx.x;
    const int l15 = lane & 15, l4 = lane >> 4;
    // XCD-aware bijective swizzle: all 6 heads of a window land on the SAME XCD.
    const int wh = (blockIdx.x & 7) * ((NWIN * NHEAD) >> 3) + (blockIdx.x >> 3);
    const int win = wh / 6;
    const int h = wh - win * 6;
    const bf16_t* ywin = ywf + (size_t)win * 12288;

    bf16_t* tb = scr;           // q/k transpose buf (stride 40), later P (stride 64, swizzled)
    bf16_t* vtb = scr + 4096;   // [32 d][64 tok] stride 72

    // ---- fused QKV GEMM: A-frags loaded ONCE per kk; 3 accumulator sets ----
    f32x4 aQ[4][2] = {}, aK[4][2] = {}, aV[4][2] = {};
#pragma unroll
    for (int kk = 0; kk < 6; ++kk) {
        bf16x8 a[4];
#pragma unroll
        for (int mt = 0; mt < 4; ++mt)
            a[mt] = *reinterpret_cast<const bf16x8*>(ywin + ((kk * 4 + mt) << 9) + lane * 8);
        bf16x8 bq[2], bk2[2], bv[2];
#pragma unroll
        for (int nt = 0; nt < 2; ++nt) {
            bq[nt] = *reinterpret_cast<const bf16x8*>(
                qkvwf + (size_t)(((((h) * 6 + kk) << 1) + nt) << 9) + lane * 8);
            bk2[nt] = *reinterpret_cast<const bf16x8*>(
                qkvwf + (size_t)(((((6 + h) * 6 + kk) << 1) + nt) << 9) + lane * 8);
            bv[nt] = *reinterpret_cast<const bf16x8*>(
                qkvwf + (size_t)(((((12 + h) * 6 + kk) << 1) + nt) << 9) + lane * 8);
        }
        __builtin_amdgcn_s_setprio(1);
#pragma unroll
        for (int mt = 0; mt < 4; ++mt)
#pragma unroll
            for (int nt = 0; nt < 2; ++nt) {
                aQ[mt][nt] = MFMA16x16(a[mt], bq[nt], aQ[mt][nt]);
                aK[mt][nt] = MFMA16x16(a[mt], bk2[nt], aK[mt][nt]);
                aV[mt][nt] = MFMA16x16(a[mt], bv[nt], aV[mt][nt]);
            }
        __builtin_amdgcn_s_setprio(0);
    }

    // ---- V epilogue -> vtb[d][tok] ----
#pragma unroll
    for (int nt = 0; nt < 2; ++nt) {
        const int d = nt * 16 + l15;
        const float bias = qkvb[(12 + h) * 32 + d];
#pragma unroll
        for (int mt = 0; mt < 4; ++mt)
#pragma unroll
            for (int r = 0; r < 4; ++r)
                vtb[d * 72 + mt * 16 + l4 * 4 + r] = (bf16_t)(aV[mt][nt][r] + bias);
    }
    // ---- Q epilogue -> tb[tok][d] stride 40, then load aq frags ----
#pragma unroll
    for (int nt = 0; nt < 2; ++nt) {
        const int d = nt * 16 + l15;
        const float bias = qkvb[h * 32 + d];
#pragma unroll
        for (int mt = 0; mt < 4; ++mt)
#pragma unroll
            for (int r = 0; r < 4; ++r)
                tb[(mt * 16 + l4 * 4 + r) * 40 + d] =
                    (bf16_t)((aQ[mt][nt][r] + bias) * 0.17677669529663689f);
    }
    bf16x8 aq[4];
#pragma unroll
    for (int mt = 0; mt < 4; ++mt)
        aq[mt] = *reinterpret_cast<const bf16x8*>(&tb[(mt * 16 + l15) * 40 + l4 * 8]);

    // ---- K epilogue -> tb (single-wave in-order DS, overwrite OK) ----
#pragma unroll
    for (int nt = 0; nt < 2; ++nt) {
        const int d = nt * 16 + l15;
        const float bias = qkvb[(6 + h) * 32 + d];
#pragma unroll
        for (int mt = 0; mt < 4; ++mt)
#pragma unroll
            for (int r = 0; r < 4; ++r)
                tb[(mt * 16 + l4 * 4 + r) * 40 + d] = (bf16_t)(aK[mt][nt][r] + bias);
    }
    bf16x8 bk[4];
#pragma unroll
    for (int nt = 0; nt < 4; ++nt)
        bk[nt] = *reinterpret_cast<const bf16x8*>(&tb[(nt * 16 + l15) * 40 + l4 * 8]);

    // ---- S = q @ k^T : 64x64, K=32 ----
    f32x4 s[4][4] = {};
    __builtin_amdgcn_s_setprio(1);
#pragma unroll
    for (int mt = 0; mt < 4; ++mt)
#pragma unroll
        for (int nt = 0; nt < 4; ++nt)
            s[mt][nt] = MFMA16x16(aq[mt], bk[nt], s[mt][nt]);
    __builtin_amdgcn_s_setprio(0);

    // ---- rel bias + shift mask + softmax; P XOR-swizzled into tb ----
    const int hb = (win >> 3) & 7, wb = win & 7;
    int colc[4], colreg[4];
#pragma unroll
    for (int nt = 0; nt < 4; ++nt) {
        const int m = nt * 16 + l15;
        const int mh = m >> 3, mw = m & 7;
        colc[nt] = mh * 15 + mw;
        const int gh = hb * 8 + mh, gw = wb * 8 + mw;
        const int rh = (gh < 56) ? 0 : ((gh < 60) ? 1 : 2);
        const int rw = (gw < 56) ? 0 : ((gw < 60) ? 1 : 2);
        colreg[nt] = rh * 3 + rw;
    }
#pragma unroll
    for (int mt = 0; mt < 4; ++mt) {
#pragma unroll
        for (int r = 0; r < 4; ++r) {
            const int n = mt * 16 + l4 * 4 + r;
            const int nh = n >> 3, nw = n & 7;
            const int rowc = nh * 15 + nw + 112;
            const int gh = hb * 8 + nh, gw = wb * 8 + nw;
            const int rh = (gh < 56) ? 0 : ((gh < 60) ? 1 : 2);
            const int rw = (gw < 56) ? 0 : ((gw < 60) ? 1 : 2);
            const int rreg = rh * 3 + rw;
            float vals[4];
            float mx = -1e30f;
#pragma unroll
            for (int nt = 0; nt < 4; ++nt) {
                float v = s[mt][nt][r] + relb[(rowc - colc[nt]) * NHEAD + h];
                if (rreg != colreg[nt]) v -= 100.0f;
                vals[nt] = v;
                mx = fmaxf(mx, v);
            }
            mx = fmaxf(mx, __shfl_xor(mx, 1));
            mx = fmaxf(mx, __shfl_xor(mx, 2));
            mx = fmaxf(mx, __shfl_xor(mx, 4));
            mx = fmaxf(mx, __shfl_xor(mx, 8));
            float sum = 0.f;
#pragma unroll
            for (int nt = 0; nt < 4; ++nt) {
                vals[nt] = __expf(vals[nt] - mx);
                sum += vals[nt];
            }
            sum += __shfl_xor(sum, 1);
            sum += __shfl_xor(sum, 2);
            sum += __shfl_xor(sum, 4);
            sum += __shfl_xor(sum, 8);
            const float inv = 1.0f / sum;
            const int nsw = n & 7;
#pragma unroll
            for (int nt = 0; nt < 4; ++nt) {
                const int tk = nt * 16 + l15;
                tb[n * 64 + (((tk >> 3) ^ nsw) << 3) + (tk & 7)] = (bf16_t)(vals[nt] * inv);
            }
        }
    }

    // ---- O = P @ V : 64x32, K=64 ----
    f32x4 o[4][2] = {};
#pragma unroll
    for (int kk = 0; kk < 2; ++kk) {
        bf16x8 a[4], b[2];
#pragma unroll
        for (int mt = 0; mt < 4; ++mt) {
            const int tq = mt * 16 + l15;
            a[mt] = *reinterpret_cast<const bf16x8*>(&tb[tq * 64 + (((kk * 4 + l4) ^ (tq & 7)) << 3)]);
        }
#pragma unroll
        for (int nt = 0; nt < 2; ++nt)
            b[nt] = *reinterpret_cast<const bf16x8*>(&vtb[(nt * 16 + l15) * 72 + kk * 32 + l4 * 8]);
        __builtin_amdgcn_s_setprio(1);
#pragma unroll
        for (int mt = 0; mt < 4; ++mt)
#pragma unroll
            for (int nt = 0; nt < 2; ++nt)
                o[mt][nt] = MFMA16x16(a[mt], b[nt], o[mt][nt]);
        __builtin_amdgcn_s_setprio(0);
    }

    // ---- stage O -> tb[tok][40] (P dead), then frag-linear coalesced store ----
#pragma unroll
    for (int mt = 0; mt < 4; ++mt)
#pragma unroll
        for (int nt = 0; nt < 2; ++nt)
#pragma unroll
            for (int r = 0; r < 4; ++r) {
                const int n = mt * 16 + l4 * 4 + r;
                tb[n * 40 + nt * 16 + l15] = (bf16_t)o[mt][nt][r];
            }
    bf16_t* op = awf + (size_t)win * 12288 + ((size_t)h << 11);
#pragma unroll
    for (int mt = 0; mt < 4; ++mt) {
        const bf16x8 v = *reinterpret_cast<const bf16x8*>(&tb[(mt * 16 + l15) * 40 + l4 * 8]);
        *reinterpret_cast<bf16x8*>(op + (mt << 9) + lane * 8) = v;
    }
}

// ---------------- proj (frag-linear A from awf, no LDS) + win-reverse + residual ----------------
__global__ __launch_bounds__(256) void proj_kernel(const bf16_t* __restrict__ awf,
                                                   const bf16_t* __restrict__ pwf,
                                                   const float* __restrict__ pbias,
                                                   const float* __restrict__ x,
                                                   float* __restrict__ x2) {
    const int tid = threadIdx.x;
    const int lane = tid & 63;
    const int wv = tid >> 6;
    const int win = blockIdx.x;
    const int l15 = lane & 15, l4 = lane >> 4;
    const bf16_t* awin = awf + (size_t)win * 12288;

    const int n0 = wv * 48;
    f32x4 acc[4][3] = {};
    for (int kk = 0; kk < 6; ++kk) {
        bf16x8 a[4], b[3];
#pragma unroll
        for (int mt = 0; mt < 4; ++mt)
            a[mt] = *reinterpret_cast<const bf16x8*>(awin + ((kk * 4 + mt) << 9) + lane * 8);
#pragma unroll
        for (int nt = 0; nt < 3; ++nt)
            b[nt] = *reinterpret_cast<const bf16x8*>(
                pwf + (size_t)(((wv * 6 + kk) * 3 + nt) << 9) + lane * 8);
#pragma unroll
        for (int mt = 0; mt < 4; ++mt)
#pragma unroll
            for (int nt = 0; nt < 3; ++nt)
                acc[mt][nt] = MFMA16x16(a[mt], b[nt], acc[mt][nt]);
    }
    const int b_ = win >> 6, hb = (win >> 3) & 7, wb = win & 7;
#pragma unroll
    for (int mt = 0; mt < 4; ++mt)
#pragma unroll
        for (int r = 0; r < 4; ++r) {
            const int n = mt * 16 + l4 * 4 + r;
            const int th = n >> 3, tw = n & 7;
            const int hh = (hb * 8 + th + 4) & 63;
            const int ww = (wb * 8 + tw + 4) & 63;
            const size_t row = ((size_t)(b_ * 64 + hh) * 64 + ww) * DIM;
#pragma unroll
            for (int nt = 0; nt < 3; ++nt) {
                const int col = n0 + nt * 16 + l15;
                x2[row + col] = acc[mt][nt][r] + pbias[col] + x[row + col];
            }
        }
}

// fast GELU, tanh form
__device__ __forceinline__ float gelu_f(float v) {
    const float x2 = v * v;
    const float inner = fmaf(0.044715f * x2, v, v);
    const float e = __expf(inner * 1.5957691216057308f);
    const float r = __builtin_amdgcn_rcpf(e + 1.0f);
    return v - v * r;
}

// ---------------- fused LN2 + MLP (round-14/16 proven body, (256,3)) ----------------
__global__ __launch_bounds__(256, 3) void mlp_kernel(const float* __restrict__ g,
                                                     const float* __restrict__ bta,
                                                     const bf16_t* __restrict__ w1f,
                                                     const float* __restrict__ b1,
                                                     const bf16_t* __restrict__ w2f,
                                                     const float* __restrict__ b2,
                                                     float* __restrict__ xout) {
    __shared__ bf16_t z_s[64][200];
    __shared__ bf16_t h_s[64][200];
    const int tid = threadIdx.x, lane = tid & 63, wv = tid >> 6;
    const int l15 = lane & 15, l4 = lane >> 4;
    const size_t t0 = (size_t)blockIdx.x * 64;
    const int n0 = wv * 48;

    // ---- LN2 on this block's 64 rows of x2 -> z_s ----
    {
        const float gv0 = g[lane], gv1 = g[lane + 64], gv2 = g[lane + 128];
        const float bv0 = bta[lane], bv1 = bta[lane + 64], bv2 = bta[lane + 128];
        for (int i = 0; i < 16; ++i) {
            const int n = wv * 16 + i;
            const size_t src = (t0 + n) * DIM;
            const float v0 = xout[src + lane], v1 = xout[src + lane + 64], v2 = xout[src + lane + 128];
            float sm = v0 + v1 + v2;
            float q = v0 * v0 + v1 * v1 + v2 * v2;
#pragma unroll
            for (int m = 1; m < 64; m <<= 1) {
                sm += __shfl_xor(sm, m);
                q += __shfl_xor(q, m);
            }
            const float mu = sm * (1.0f / DIM);
            const float inv = rsqrtf(q * (1.0f / DIM) - mu * mu + 1e-5f);
            z_s[n][lane]       = (bf16_t)((v0 - mu) * inv * gv0 + bv0);
            z_s[n][lane + 64]  = (bf16_t)((v1 - mu) * inv * gv1 + bv1);
            z_s[n][lane + 128] = (bf16_t)((v2 - mu) * inv * gv2 + bv2);
        }
    }
    __syncthreads();

    f32x4 acc_o[4][3] = {};
    for (int kc = 0; kc < 4; ++kc) {
        const int fb = (kc * 4 + wv) * 18;
        f32x4 hacc[4][3] = {};
#pragma unroll
        for (int kk = 0; kk < 6; ++kk) {
            const int c0 = kk * 32 + l4 * 8;
            bf16x8 a[4], b[3];
#pragma unroll
            for (int mt = 0; mt < 4; ++mt)
                a[mt] = *reinterpret_cast<const bf16x8*>(&z_s[mt * 16 + l15][c0]);
#pragma unroll
            for (int nt = 0; nt < 3; ++nt)
                b[nt] = *reinterpret_cast<const bf16x8*>(
                    w1f + (size_t)((fb + kk * 3 + nt) << 9) + lane * 8);
#pragma unroll
            for (int mt = 0; mt < 4; ++mt)
#pragma unroll
                for (int nt = 0; nt < 3; ++nt)
                    hacc[mt][nt] = MFMA16x16(a[mt], b[nt], hacc[mt][nt]);
        }
        __syncthreads();  // previous GEMM2 done reading h_s
#pragma unroll
        for (int mt = 0; mt < 4; ++mt)
#pragma unroll
            for (int r = 0; r < 4; ++r) {
                const int n = mt * 16 + l4 * 4 + r;
#pragma unroll
                for (int nt = 0; nt < 3; ++nt) {
                    const int col = n0 + nt * 16 + l15;
                    h_s[n][col] = (bf16_t)gelu_f(hacc[mt][nt][r] + b1[kc * 192 + col]);
                }
            }
        __syncthreads();
        // GEMM2: acc_o += h_chunk @ w2_chunk^T
#pragma unroll
        for (int kk = 0; kk < 6; ++kk) {
            const int c0 = kk * 32 + l4 * 8;
            bf16x8 a[4], b[3];
#pragma unroll
            for (int mt = 0; mt < 4; ++mt)
                a[mt] = *reinterpret_cast<const bf16x8*>(&h_s[mt * 16 + l15][c0]);
#pragma unroll
            for (int nt = 0; nt < 3; ++nt)
                b[nt] = *reinterpret_cast<const bf16x8*>(
                    w2f + (size_t)((fb + kk * 3 + nt) << 9) + lane * 8);
#pragma unroll
            for (int mt = 0; mt < 4; ++mt)
#pragma unroll
                for (int nt = 0; nt < 3; ++nt)
                    acc_o[mt][nt] = MFMA16x16(a[mt], b[nt], acc_o[mt][nt]);
        }
    }
#pragma unroll
    for (int mt = 0; mt < 4; ++mt)
#pragma unroll
        for (int r = 0; r < 4; ++r) {
            const int n = mt * 16 + l4 * 4 + r;
            const size_t addr = (t0 + n) * DIM;
#pragma unroll
            for (int nt = 0; nt < 3; ++nt) {
                const int col = n0 + nt * 16 + l15;
                xout[addr + col] = acc_o[mt][nt][r] + b2[col] + xout[addr + col];
            }
        }
}

extern "C" void kernel_launch(void* const* d_in, const int* in_sizes, int n_in,
                              void* d_out, int out_size, void* d_ws, size_t ws_size,
                              hipStream_t stream) {
    const float* x      = (const float*)d_in[0];
    const float* ln1_g  = (const float*)d_in[1];
    const float* ln1_b  = (const float*)d_in[2];
    const float* qkv_w  = (const float*)d_in[3];
    const float* qkv_b  = (const float*)d_in[4];
    const float* proj_w = (const float*)d_in[5];
    const float* proj_b = (const float*)d_in[6];
    const float* relb   = (const float*)d_in[7];
    const float* ln2_g  = (const float*)d_in[8];
    const float* ln2_b  = (const float*)d_in[9];
    const float* mlp_w1 = (const float*)d_in[10];
    const float* mlp_b1 = (const float*)d_in[11];
    const float* mlp_w2 = (const float*)d_in[12];
    const float* mlp_b2 = (const float*)d_in[13];
    float* out = (float*)d_out;

    char* ws = (char*)d_ws;
    bf16_t* qkvwf = (bf16_t*)(ws + 0);                       // 221184 B
    bf16_t* pwf   = (bf16_t*)(ws + 221184);                  // 73728 B
    bf16_t* w1f   = (bf16_t*)(ws + 294912);                  // 294912 B
    bf16_t* w2f   = (bf16_t*)(ws + 589824);                  // 294912 B
    bf16_t* bufA  = (bf16_t*)(ws + 884736);                  // ywf (frag-linear)
    bf16_t* bufB  = (bf16_t*)(ws + 884736 + 50331648);       // awf (frag-linear attn out)

    cvt_all<<<216, 256, 0, stream>>>(qkv_w, proj_w, mlp_w1, mlp_w2, qkvwf, pwf, w1f, w2f);

    ln_win_kernel<<<NWIN, 256, 0, stream>>>(x, ln1_g, ln1_b, bufA);
    attn_kernel<<<NWIN * NHEAD, 64, 0, stream>>>(bufA, qkvwf, qkv_b, relb, bufB);
    proj_kernel<<<NWIN, 256, 0, stream>>>(bufB, pwf, proj_b, x, out);
    mlp_kernel<<<2048, 256, 0, stream>>>(ln2_g, ln2_b, w1f, mlp_b1, w2f, mlp_b2, out);
}